// Round 1
// baseline (287.455 us; speedup 1.0000x reference)
//
#include <hip/hip_runtime.h>
#include <stdint.h>

#define K_DIM 4096
#define N_DIM 4096
#define SIGMA 20.0f
#define EPSQ 1e-8f

typedef __attribute__((ext_vector_type(4))) int i32x4;

// global_load_lds width-16 helper (addrspace casts: generic->AS1 / ->AS3)
#define GLDS16(gp, lp)                                                         \
  __builtin_amdgcn_global_load_lds(                                            \
      (const __attribute__((address_space(1))) unsigned int*)(const void*)(gp),\
      (__attribute__((address_space(3))) unsigned int*)(void*)(lp), 16, 0, 0)

// ---------------------------------------------------------------------------
// Kernel 1: per-row absmax -> row_scale, outlier column mask, quantize x->int8
// one block per row m; 256 threads; 4 float4 per thread (K=4096)
// ---------------------------------------------------------------------------
__global__ __launch_bounds__(256) void k_rowquant(
    const float* __restrict__ x, float* __restrict__ row_scale,
    int* __restrict__ mask, int8_t* __restrict__ qx)
{
  const int m = blockIdx.x;
  const int t = threadIdx.x;
  const float4* xr = (const float4*)(x + (size_t)m * K_DIM);
  float4 v[4];
  float amax = 0.0f;
#pragma unroll
  for (int i = 0; i < 4; ++i) {
    v[i] = xr[t + i * 256];
    float a0 = fabsf(v[i].x), a1 = fabsf(v[i].y);
    float a2 = fabsf(v[i].z), a3 = fabsf(v[i].w);
    amax = fmaxf(amax, fmaxf(fmaxf(a0, a1), fmaxf(a2, a3)));
    int kbase = (t + i * 256) * 4;
    if (a0 > SIGMA) atomicOr(&mask[kbase + 0], 1);
    if (a1 > SIGMA) atomicOr(&mask[kbase + 1], 1);
    if (a2 > SIGMA) atomicOr(&mask[kbase + 2], 1);
    if (a3 > SIGMA) atomicOr(&mask[kbase + 3], 1);
  }
#pragma unroll
  for (int off = 32; off > 0; off >>= 1)
    amax = fmaxf(amax, __shfl_down(amax, off, 64));
  __shared__ float smax[4];
  __shared__ float sscale;
  if ((t & 63) == 0) smax[t >> 6] = amax;
  __syncthreads();
  if (t == 0) {
    float ms = fmaxf(fmaxf(smax[0], smax[1]), fmaxf(smax[2], smax[3]));
    float rs = fmaxf(ms / 127.0f, EPSQ);  // IEEE divide: bit-match jnp
    sscale = rs;
    row_scale[m] = rs;
  }
  __syncthreads();
  const float rs = sscale;
  uint32_t* qxo = (uint32_t*)(qx + (size_t)m * K_DIM);
#pragma unroll
  for (int i = 0; i < 4; ++i) {
    int q0 = (int)rintf(fminf(fmaxf(v[i].x / rs, -128.0f), 127.0f));
    int q1 = (int)rintf(fminf(fmaxf(v[i].y / rs, -128.0f), 127.0f));
    int q2 = (int)rintf(fminf(fmaxf(v[i].z / rs, -128.0f), 127.0f));
    int q3 = (int)rintf(fminf(fmaxf(v[i].w / rs, -128.0f), 127.0f));
    uint32_t packed = (uint32_t)(q0 & 0xff) | ((uint32_t)(q1 & 0xff) << 8) |
                      ((uint32_t)(q2 & 0xff) << 16) | ((uint32_t)(q3 & 0xff) << 24);
    qxo[t + i * 256] = packed;
  }
}

// ---------------------------------------------------------------------------
// Kernel 2: compact mask -> outlier column list + count
// ---------------------------------------------------------------------------
__global__ __launch_bounds__(256) void k_compact(
    const int* __restrict__ mask, int* __restrict__ outlist,
    int* __restrict__ count)
{
  int k = blockIdx.x * 256 + threadIdx.x;
  if (mask[k]) {
    int idx = atomicAdd(count, 1);
    outlist[idx] = k;
  }
}

// ---------------------------------------------------------------------------
// Kernel 3: weight quant: zero outlier cols, per-row absmax -> q_scale, int8
// one block per row n
// ---------------------------------------------------------------------------
__global__ __launch_bounds__(256) void k_wquant(
    const float* __restrict__ w, const int* __restrict__ mask,
    float* __restrict__ q_scale, int8_t* __restrict__ qw)
{
  const int n = blockIdx.x;
  const int t = threadIdx.x;
  const float4* wr = (const float4*)(w + (size_t)n * K_DIM);
  const int4* mr = (const int4*)mask;
  float4 v[4];
  float amax = 0.0f;
#pragma unroll
  for (int i = 0; i < 4; ++i) {
    float4 vv = wr[t + i * 256];
    int4 mm = mr[t + i * 256];
    vv.x = mm.x ? 0.0f : vv.x;
    vv.y = mm.y ? 0.0f : vv.y;
    vv.z = mm.z ? 0.0f : vv.z;
    vv.w = mm.w ? 0.0f : vv.w;
    v[i] = vv;
    amax = fmaxf(amax, fmaxf(fmaxf(fabsf(vv.x), fabsf(vv.y)),
                             fmaxf(fabsf(vv.z), fabsf(vv.w))));
  }
#pragma unroll
  for (int off = 32; off > 0; off >>= 1)
    amax = fmaxf(amax, __shfl_down(amax, off, 64));
  __shared__ float smax[4];
  __shared__ float sscale;
  if ((t & 63) == 0) smax[t >> 6] = amax;
  __syncthreads();
  if (t == 0) {
    float ms = fmaxf(fmaxf(smax[0], smax[1]), fmaxf(smax[2], smax[3]));
    float qs = fmaxf(ms / 127.0f, EPSQ);
    sscale = qs;
    q_scale[n] = qs;
  }
  __syncthreads();
  const float qs = sscale;
  uint32_t* qwo = (uint32_t*)(qw + (size_t)n * K_DIM);
#pragma unroll
  for (int i = 0; i < 4; ++i) {
    int q0 = (int)rintf(fminf(fmaxf(v[i].x / qs, -128.0f), 127.0f));
    int q1 = (int)rintf(fminf(fmaxf(v[i].y / qs, -128.0f), 127.0f));
    int q2 = (int)rintf(fminf(fmaxf(v[i].z / qs, -128.0f), 127.0f));
    int q3 = (int)rintf(fminf(fmaxf(v[i].w / qs, -128.0f), 127.0f));
    uint32_t packed = (uint32_t)(q0 & 0xff) | ((uint32_t)(q1 & 0xff) << 8) |
                      ((uint32_t)(q2 & 0xff) << 16) | ((uint32_t)(q3 & 0xff) << 24);
    qwo[t + i * 256] = packed;
  }
}

// ---------------------------------------------------------------------------
// Kernel 4: int8 GEMM (m97 structure) + fused dequant + outlier corr + bias
// 128x128 tile, BK=64, 256 threads = 4 waves in 2x2, each wave 4x4 of 16x16
// C[m][n] = sum_k qx[m][k]*qw[n][k]  (both row-major K-inner: B^T layout)
// ---------------------------------------------------------------------------
__global__ __launch_bounds__(256) void k_gemm(
    const int8_t* __restrict__ qx, const int8_t* __restrict__ qw,
    const float* __restrict__ row_scale, const float* __restrict__ q_scale,
    const float* __restrict__ bias,
    const float* __restrict__ x, const float* __restrict__ w,
    const int* __restrict__ outlist, const int* __restrict__ outcount,
    float* __restrict__ out)
{
  __shared__ int8_t As[128 * 64];   // row stride 64B
  __shared__ int8_t Bs[128 * 64];
  __shared__ float xsh[128][8];
  __shared__ float wsh[128][8];

  const int t = threadIdx.x;
  const int m0 = blockIdx.y * 128;
  const int n0 = blockIdx.x * 128;

  const int lane = t & 63;
  const int wave = t >> 6;
  const int wm = (wave & 1) * 64;
  const int wn = (wave >> 1) * 64;
  const int lrow = lane & 15;
  const int kg = lane >> 4;  // 0..3

  i32x4 acc[4][4] = {};

  // staging: thread t loads 16B at row (t>>2), col chunk (t&3)*16; two halves
  const int sr = t >> 2;
  const int sc = (t & 3) * 16;
  const int8_t* gA = qx + (size_t)(m0 + sr) * K_DIM + sc;
  const int8_t* gB = qw + (size_t)(n0 + sr) * K_DIM + sc;

  for (int k0 = 0; k0 < K_DIM; k0 += 64) {
    GLDS16(gA + k0,                        As + t * 16);
    GLDS16(gA + (size_t)64 * K_DIM + k0,   As + 4096 + t * 16);
    GLDS16(gB + k0,                        Bs + t * 16);
    GLDS16(gB + (size_t)64 * K_DIM + k0,   Bs + 4096 + t * 16);
    __syncthreads();

    i32x4 af[4], bf[4];
#pragma unroll
    for (int i = 0; i < 4; ++i)
      af[i] = *(const i32x4*)(As + (wm + i * 16 + lrow) * 64 + kg * 16);
#pragma unroll
    for (int j = 0; j < 4; ++j)
      bf[j] = *(const i32x4*)(Bs + (wn + j * 16 + lrow) * 64 + kg * 16);
#pragma unroll
    for (int i = 0; i < 4; ++i)
#pragma unroll
      for (int j = 0; j < 4; ++j)
        acc[i][j] = __builtin_amdgcn_mfma_i32_16x16x64_i8(af[i], bf[j], acc[i][j], 0, 0, 0);
    __syncthreads();
  }

  // ---- epilogue: stage outlier x / w slices into LDS ----
  const int cnt = *outcount;
  const int cs = cnt < 8 ? cnt : 8;
#pragma unroll
  for (int u = 0; u < 4; ++u) {
    int idx = t * 4 + u;   // 0..1023
    int rr = idx >> 3;     // 0..127
    int oo = idx & 7;
    float xv = 0.0f, wv = 0.0f;
    if (oo < cs) {
      int kcol = outlist[oo];
      xv = x[(size_t)(m0 + rr) * K_DIM + kcol];
      wv = w[(size_t)(n0 + rr) * K_DIM + kcol];
    }
    xsh[rr][oo] = xv;
    wsh[rr][oo] = wv;
  }
  __syncthreads();

  float qs[4], bv[4];
  int gn[4];
#pragma unroll
  for (int j = 0; j < 4; ++j) {
    gn[j] = n0 + wn + j * 16 + lrow;
    qs[j] = q_scale[gn[j]];
    bv[j] = bias[gn[j]];
  }

  // C/D layout: col = lane&15, row = (lane>>4)*4 + reg  [m89/m101, dtype-indep]
#pragma unroll
  for (int i = 0; i < 4; ++i) {
#pragma unroll
    for (int r = 0; r < 4; ++r) {
      int ml = wm + i * 16 + kg * 4 + r;
      int gm = m0 + ml;
      float rs = row_scale[gm];
      float xvv[8];
#pragma unroll
      for (int o = 0; o < 8; ++o) xvv[o] = xsh[ml][o];
#pragma unroll
      for (int j = 0; j < 4; ++j) {
        int nl = wn + j * 16 + lrow;
        float corr = 0.0f;
#pragma unroll
        for (int o = 0; o < 8; ++o) corr += xvv[o] * wsh[nl][o];
        for (int o = 8; o < cnt; ++o)   // generality fallback (cold in practice)
          corr += x[(size_t)gm * K_DIM + outlist[o]] *
                  w[(size_t)gn[j] * K_DIM + outlist[o]];
        float val = (float)acc[i][j][r] * rs * qs[j] + corr + bv[j];
        out[(size_t)gm * N_DIM + gn[j]] = val;
      }
    }
  }
}

// ---------------------------------------------------------------------------
extern "C" void kernel_launch(void* const* d_in, const int* in_sizes, int n_in,
                              void* d_out, int out_size, void* d_ws, size_t ws_size,
                              hipStream_t stream) {
  const float* x = (const float*)d_in[0];      // [M,K] fp32 (M = B*S)
  const float* w = (const float*)d_in[1];      // [N,K] fp32
  const float* bias = (const float*)d_in[2];   // [N]
  float* out = (float*)d_out;                  // [M,N] fp32
  const int M = in_sizes[0] / K_DIM;           // 4096

  // workspace layout
  char* ws = (char*)d_ws;
  int* mask = (int*)(ws);                          // 16 KB
  int* count = (int*)(ws + 16384);                 // 4 B (memset region)
  int* outlist = (int*)(ws + 20480);               // 16 KB
  float* row_scale = (float*)(ws + 36864);         // 16 KB
  float* q_scale = (float*)(ws + 53248);           // 16 KB
  int8_t* qx = (int8_t*)(ws + 131072);             // M*K int8 = 16 MB
  int8_t* qw = (int8_t*)(ws + 131072 + (size_t)M * K_DIM);  // N*K int8 = 16 MB

  hipMemsetAsync(ws, 0, 20480, stream);  // mask + count
  k_rowquant<<<M, 256, 0, stream>>>(x, row_scale, mask, qx);
  k_compact<<<K_DIM / 256, 256, 0, stream>>>(mask, outlist, count);
  k_wquant<<<N_DIM, 256, 0, stream>>>(w, mask, q_scale, qw);
  dim3 grid(N_DIM / 128, M / 128);
  k_gemm<<<grid, dim3(256, 1, 1), 0, stream>>>(qx, qw, row_scale, q_scale, bias,
                                               x, w, outlist, count, out);
}

// Round 2
// 275.666 us; speedup vs baseline: 1.0428x; 1.0428x over previous
//
#include <hip/hip_runtime.h>
#include <stdint.h>

#define K_DIM 4096
#define N_DIM 4096
#define SIGMA 20.0f
#define EPSQ 1e-8f

typedef __attribute__((ext_vector_type(4))) int i32x4;

// global_load_lds width-16 helper (addrspace casts: generic->AS1 / ->AS3)
#define GLDS16(gp, lp)                                                         \
  __builtin_amdgcn_global_load_lds(                                            \
      (const __attribute__((address_space(1))) unsigned int*)(const void*)(gp),\
      (__attribute__((address_space(3))) unsigned int*)(void*)(lp), 16, 0, 0)

// ---------------------------------------------------------------------------
// Kernel 1: per-row absmax -> row_scale, outlier column mask, quantize x->int8
// ---------------------------------------------------------------------------
__global__ __launch_bounds__(256) void k_rowquant(
    const float* __restrict__ x, float* __restrict__ row_scale,
    int* __restrict__ mask, int8_t* __restrict__ qx)
{
  const int m = blockIdx.x;
  const int t = threadIdx.x;
  const float4* xr = (const float4*)(x + (size_t)m * K_DIM);
  float4 v[4];
  float amax = 0.0f;
#pragma unroll
  for (int i = 0; i < 4; ++i) {
    v[i] = xr[t + i * 256];
    float a0 = fabsf(v[i].x), a1 = fabsf(v[i].y);
    float a2 = fabsf(v[i].z), a3 = fabsf(v[i].w);
    amax = fmaxf(amax, fmaxf(fmaxf(a0, a1), fmaxf(a2, a3)));
    int kbase = (t + i * 256) * 4;
    if (a0 > SIGMA) atomicOr(&mask[kbase + 0], 1);
    if (a1 > SIGMA) atomicOr(&mask[kbase + 1], 1);
    if (a2 > SIGMA) atomicOr(&mask[kbase + 2], 1);
    if (a3 > SIGMA) atomicOr(&mask[kbase + 3], 1);
  }
#pragma unroll
  for (int off = 32; off > 0; off >>= 1)
    amax = fmaxf(amax, __shfl_down(amax, off, 64));
  __shared__ float smax[4];
  __shared__ float sscale;
  if ((t & 63) == 0) smax[t >> 6] = amax;
  __syncthreads();
  if (t == 0) {
    float ms = fmaxf(fmaxf(smax[0], smax[1]), fmaxf(smax[2], smax[3]));
    float rs = fmaxf(ms / 127.0f, EPSQ);  // IEEE divide: bit-match jnp
    sscale = rs;
    row_scale[m] = rs;
  }
  __syncthreads();
  const float rs = sscale;
  uint32_t* qxo = (uint32_t*)(qx + (size_t)m * K_DIM);
#pragma unroll
  for (int i = 0; i < 4; ++i) {
    int q0 = (int)rintf(fminf(fmaxf(v[i].x / rs, -128.0f), 127.0f));
    int q1 = (int)rintf(fminf(fmaxf(v[i].y / rs, -128.0f), 127.0f));
    int q2 = (int)rintf(fminf(fmaxf(v[i].z / rs, -128.0f), 127.0f));
    int q3 = (int)rintf(fminf(fmaxf(v[i].w / rs, -128.0f), 127.0f));
    uint32_t packed = (uint32_t)(q0 & 0xff) | ((uint32_t)(q1 & 0xff) << 8) |
                      ((uint32_t)(q2 & 0xff) << 16) | ((uint32_t)(q3 & 0xff) << 24);
    qxo[t + i * 256] = packed;
  }
}

// ---------------------------------------------------------------------------
// Kernel 2: compact mask -> outlier column list + count
// ---------------------------------------------------------------------------
__global__ __launch_bounds__(256) void k_compact(
    const int* __restrict__ mask, int* __restrict__ outlist,
    int* __restrict__ count)
{
  int k = blockIdx.x * 256 + threadIdx.x;
  if (mask[k]) {
    int idx = atomicAdd(count, 1);
    outlist[idx] = k;
  }
}

// ---------------------------------------------------------------------------
// Kernel 3: weight quant: zero outlier cols, per-row absmax -> q_scale, int8
// ---------------------------------------------------------------------------
__global__ __launch_bounds__(256) void k_wquant(
    const float* __restrict__ w, const int* __restrict__ mask,
    float* __restrict__ q_scale, int8_t* __restrict__ qw)
{
  const int n = blockIdx.x;
  const int t = threadIdx.x;
  const float4* wr = (const float4*)(w + (size_t)n * K_DIM);
  const int4* mr = (const int4*)mask;
  float4 v[4];
  float amax = 0.0f;
#pragma unroll
  for (int i = 0; i < 4; ++i) {
    float4 vv = wr[t + i * 256];
    int4 mm = mr[t + i * 256];
    vv.x = mm.x ? 0.0f : vv.x;
    vv.y = mm.y ? 0.0f : vv.y;
    vv.z = mm.z ? 0.0f : vv.z;
    vv.w = mm.w ? 0.0f : vv.w;
    v[i] = vv;
    amax = fmaxf(amax, fmaxf(fmaxf(fabsf(vv.x), fabsf(vv.y)),
                             fmaxf(fabsf(vv.z), fabsf(vv.w))));
  }
#pragma unroll
  for (int off = 32; off > 0; off >>= 1)
    amax = fmaxf(amax, __shfl_down(amax, off, 64));
  __shared__ float smax[4];
  __shared__ float sscale;
  if ((t & 63) == 0) smax[t >> 6] = amax;
  __syncthreads();
  if (t == 0) {
    float ms = fmaxf(fmaxf(smax[0], smax[1]), fmaxf(smax[2], smax[3]));
    float qs = fmaxf(ms / 127.0f, EPSQ);
    sscale = qs;
    q_scale[n] = qs;
  }
  __syncthreads();
  const float qs = sscale;
  uint32_t* qwo = (uint32_t*)(qw + (size_t)n * K_DIM);
#pragma unroll
  for (int i = 0; i < 4; ++i) {
    int q0 = (int)rintf(fminf(fmaxf(v[i].x / qs, -128.0f), 127.0f));
    int q1 = (int)rintf(fminf(fmaxf(v[i].y / qs, -128.0f), 127.0f));
    int q2 = (int)rintf(fminf(fmaxf(v[i].z / qs, -128.0f), 127.0f));
    int q3 = (int)rintf(fminf(fmaxf(v[i].w / qs, -128.0f), 127.0f));
    uint32_t packed = (uint32_t)(q0 & 0xff) | ((uint32_t)(q1 & 0xff) << 8) |
                      ((uint32_t)(q2 & 0xff) << 16) | ((uint32_t)(q3 & 0xff) << 24);
    qwo[t + i * 256] = packed;
  }
}

// ---------------------------------------------------------------------------
// Kernel 4: int8 GEMM, BK=128, 128B LDS row stride + XOR chunk swizzle
// (conflict-free quarter-wave ds_read_b128), fused dequant + outliers + bias.
// 128x128 tile, 256 threads = 4 waves (2x2), each wave 4x4 of 16x16x64.
// Swizzle: LDS chunk c_phys = c_log ^ (row & 7); applied on the GLOBAL source
// side for staging (GLDS dest must stay base + lane*16), and on the LDS read
// offsets (loop-invariant, precomputed).
// ---------------------------------------------------------------------------
__global__ __launch_bounds__(256) void k_gemm(
    const int8_t* __restrict__ qx, const int8_t* __restrict__ qw,
    const float* __restrict__ row_scale, const float* __restrict__ q_scale,
    const float* __restrict__ bias,
    const float* __restrict__ x, const float* __restrict__ w,
    const int* __restrict__ outlist, const int* __restrict__ outcount,
    float* __restrict__ out)
{
  __shared__ int8_t As[128 * 128];   // 16 KB, row stride 128B
  __shared__ int8_t Bs[128 * 128];   // 16 KB
  __shared__ float xsh[128][8];
  __shared__ float wsh[128][8];

  const int t = threadIdx.x;
  const int m0 = blockIdx.y * 128;
  const int n0 = blockIdx.x * 128;

  const int lane = t & 63;
  const int wave = t >> 6;
  const int wm = (wave & 1) * 64;
  const int wn = (wave >> 1) * 64;
  const int lrow = lane & 15;
  const int kg = lane >> 4;  // 0..3

  i32x4 acc[4][4] = {};

  // staging geometry: slot s = q*256 + t -> row = q*32 + (t>>3), c_phys = t&7
  // logical chunk for that slot: c_log = c_phys ^ (row & 7)
  const int srow = t >> 3;                         // 0..31 (+ q*32)
  const int clog = (t & 7) ^ ((t >> 3) & 7);
  const int8_t* gA = qx + (size_t)(m0 + srow) * K_DIM + clog * 16;
  const int8_t* gB = qw + (size_t)(n0 + srow) * K_DIM + clog * 16;

  // loop-invariant LDS read offsets (swizzled)
  int offA[2][4], offB[2][4];
#pragma unroll
  for (int kh = 0; kh < 2; ++kh) {
#pragma unroll
    for (int i = 0; i < 4; ++i) {
      int rA = wm + i * 16 + lrow;
      offA[kh][i] = rA * 128 + (((kg + kh * 4) ^ (rA & 7)) * 16);
      int rB = wn + i * 16 + lrow;
      offB[kh][i] = rB * 128 + (((kg + kh * 4) ^ (rB & 7)) * 16);
    }
  }

  for (int k0 = 0; k0 < K_DIM; k0 += 128) {
    GLDS16(gA + k0,                          As + t * 16);
    GLDS16(gA + (size_t)32 * K_DIM + k0,     As + 4096 + t * 16);
    GLDS16(gA + (size_t)64 * K_DIM + k0,     As + 8192 + t * 16);
    GLDS16(gA + (size_t)96 * K_DIM + k0,     As + 12288 + t * 16);
    GLDS16(gB + k0,                          Bs + t * 16);
    GLDS16(gB + (size_t)32 * K_DIM + k0,     Bs + 4096 + t * 16);
    GLDS16(gB + (size_t)64 * K_DIM + k0,     Bs + 8192 + t * 16);
    GLDS16(gB + (size_t)96 * K_DIM + k0,     Bs + 12288 + t * 16);
    __syncthreads();

#pragma unroll
    for (int kh = 0; kh < 2; ++kh) {
      i32x4 af[4], bf[4];
#pragma unroll
      for (int i = 0; i < 4; ++i) af[i] = *(const i32x4*)(As + offA[kh][i]);
#pragma unroll
      for (int j = 0; j < 4; ++j) bf[j] = *(const i32x4*)(Bs + offB[kh][j]);
#pragma unroll
      for (int i = 0; i < 4; ++i)
#pragma unroll
        for (int j = 0; j < 4; ++j)
          acc[i][j] = __builtin_amdgcn_mfma_i32_16x16x64_i8(af[i], bf[j], acc[i][j], 0, 0, 0);
    }
    __syncthreads();
  }

  // ---- epilogue: stage outlier x / w slices into LDS ----
  const int cnt = *outcount;
  const int cs = cnt < 8 ? cnt : 8;
#pragma unroll
  for (int u = 0; u < 4; ++u) {
    int idx = t * 4 + u;   // 0..1023
    int rr = idx >> 3;     // 0..127
    int oo = idx & 7;
    float xv = 0.0f, wv = 0.0f;
    if (oo < cs) {
      int kcol = outlist[oo];
      xv = x[(size_t)(m0 + rr) * K_DIM + kcol];
      wv = w[(size_t)(n0 + rr) * K_DIM + kcol];
    }
    xsh[rr][oo] = xv;
    wsh[rr][oo] = wv;
  }
  __syncthreads();

  float qs[4], bv[4];
  int gn[4];
#pragma unroll
  for (int j = 0; j < 4; ++j) {
    gn[j] = n0 + wn + j * 16 + lrow;
    qs[j] = q_scale[gn[j]];
    bv[j] = bias[gn[j]];
  }

  // C/D layout: col = lane&15, row = (lane>>4)*4 + reg  [m89/m101, dtype-indep]
#pragma unroll
  for (int i = 0; i < 4; ++i) {
#pragma unroll
    for (int r = 0; r < 4; ++r) {
      int ml = wm + i * 16 + kg * 4 + r;
      int gm = m0 + ml;
      float rs = row_scale[gm];
      float xvv[8];
#pragma unroll
      for (int o = 0; o < 8; ++o) xvv[o] = xsh[ml][o];
#pragma unroll
      for (int j = 0; j < 4; ++j) {
        int nl = wn + j * 16 + lrow;
        float corr = 0.0f;
#pragma unroll
        for (int o = 0; o < 8; ++o) corr += xvv[o] * wsh[nl][o];
        for (int o = 8; o < cnt; ++o)   // generality fallback (cold in practice)
          corr += x[(size_t)gm * K_DIM + outlist[o]] *
                  w[(size_t)gn[j] * K_DIM + outlist[o]];
        float val = (float)acc[i][j][r] * rs * qs[j] + corr + bv[j];
        out[(size_t)gm * N_DIM + gn[j]] = val;
      }
    }
  }
}

// ---------------------------------------------------------------------------
extern "C" void kernel_launch(void* const* d_in, const int* in_sizes, int n_in,
                              void* d_out, int out_size, void* d_ws, size_t ws_size,
                              hipStream_t stream) {
  const float* x = (const float*)d_in[0];      // [M,K] fp32 (M = B*S)
  const float* w = (const float*)d_in[1];      // [N,K] fp32
  const float* bias = (const float*)d_in[2];   // [N]
  float* out = (float*)d_out;                  // [M,N] fp32
  const int M = in_sizes[0] / K_DIM;           // 4096

  // workspace layout
  char* ws = (char*)d_ws;
  int* mask = (int*)(ws);                          // 16 KB
  int* count = (int*)(ws + 16384);                 // 4 B (memset region)
  int* outlist = (int*)(ws + 20480);               // 16 KB
  float* row_scale = (float*)(ws + 36864);         // 16 KB
  float* q_scale = (float*)(ws + 53248);           // 16 KB
  int8_t* qx = (int8_t*)(ws + 131072);             // M*K int8 = 16 MB
  int8_t* qw = (int8_t*)(ws + 131072 + (size_t)M * K_DIM);  // N*K int8 = 16 MB

  hipMemsetAsync(ws, 0, 20480, stream);  // mask + count
  k_rowquant<<<M, 256, 0, stream>>>(x, row_scale, mask, qx);
  k_compact<<<K_DIM / 256, 256, 0, stream>>>(mask, outlist, count);
  k_wquant<<<N_DIM, 256, 0, stream>>>(w, mask, q_scale, qw);
  dim3 grid(N_DIM / 128, M / 128);
  k_gemm<<<grid, dim3(256, 1, 1), 0, stream>>>(qx, qw, row_scale, q_scale, bias,
                                               x, w, outlist, count, out);
}

// Round 3
// 272.622 us; speedup vs baseline: 1.0544x; 1.0112x over previous
//
#include <hip/hip_runtime.h>
#include <stdint.h>

#define K_DIM 4096
#define N_DIM 4096
#define SIGMA 20.0f
#define EPSQ 1e-8f

typedef __attribute__((ext_vector_type(4))) int i32x4;

// global_load_lds width-16 helper (addrspace casts: generic->AS1 / ->AS3)
#define GLDS16(gp, lp)                                                         \
  __builtin_amdgcn_global_load_lds(                                            \
      (const __attribute__((address_space(1))) unsigned int*)(const void*)(gp),\
      (__attribute__((address_space(3))) unsigned int*)(void*)(lp), 16, 0, 0)

// ---------------------------------------------------------------------------
// Kernel 1: per-row absmax -> row_scale, outlier column mask, quantize x->int8
// mask write is a PLAIN store (benign race: all writers store 1). atomicOr on
// 8 hot addresses serialized ~4096 RMWs each (~100us) in R1/R2.
// ---------------------------------------------------------------------------
__global__ __launch_bounds__(256) void k_rowquant(
    const float* __restrict__ x, float* __restrict__ row_scale,
    int* __restrict__ mask, int8_t* __restrict__ qx)
{
  const int m = blockIdx.x;
  const int t = threadIdx.x;
  const float4* xr = (const float4*)(x + (size_t)m * K_DIM);
  float4 v[4];
  float amax = 0.0f;
#pragma unroll
  for (int i = 0; i < 4; ++i) {
    v[i] = xr[t + i * 256];
    float a0 = fabsf(v[i].x), a1 = fabsf(v[i].y);
    float a2 = fabsf(v[i].z), a3 = fabsf(v[i].w);
    amax = fmaxf(amax, fmaxf(fmaxf(a0, a1), fmaxf(a2, a3)));
    int kbase = (t + i * 256) * 4;
    if (a0 > SIGMA) mask[kbase + 0] = 1;
    if (a1 > SIGMA) mask[kbase + 1] = 1;
    if (a2 > SIGMA) mask[kbase + 2] = 1;
    if (a3 > SIGMA) mask[kbase + 3] = 1;
  }
#pragma unroll
  for (int off = 32; off > 0; off >>= 1)
    amax = fmaxf(amax, __shfl_down(amax, off, 64));
  __shared__ float smax[4];
  __shared__ float sscale;
  if ((t & 63) == 0) smax[t >> 6] = amax;
  __syncthreads();
  if (t == 0) {
    float ms = fmaxf(fmaxf(smax[0], smax[1]), fmaxf(smax[2], smax[3]));
    float rs = fmaxf(ms / 127.0f, EPSQ);  // IEEE divide: bit-match jnp
    sscale = rs;
    row_scale[m] = rs;
  }
  __syncthreads();
  const float rs = sscale;
  uint32_t* qxo = (uint32_t*)(qx + (size_t)m * K_DIM);
#pragma unroll
  for (int i = 0; i < 4; ++i) {
    int q0 = (int)rintf(fminf(fmaxf(v[i].x / rs, -128.0f), 127.0f));
    int q1 = (int)rintf(fminf(fmaxf(v[i].y / rs, -128.0f), 127.0f));
    int q2 = (int)rintf(fminf(fmaxf(v[i].z / rs, -128.0f), 127.0f));
    int q3 = (int)rintf(fminf(fmaxf(v[i].w / rs, -128.0f), 127.0f));
    uint32_t packed = (uint32_t)(q0 & 0xff) | ((uint32_t)(q1 & 0xff) << 8) |
                      ((uint32_t)(q2 & 0xff) << 16) | ((uint32_t)(q3 & 0xff) << 24);
    qxo[t + i * 256] = packed;
  }
}

// ---------------------------------------------------------------------------
// Kernel 2: compact mask -> outlier column list + count
// ---------------------------------------------------------------------------
__global__ __launch_bounds__(256) void k_compact(
    const int* __restrict__ mask, int* __restrict__ outlist,
    int* __restrict__ count)
{
  int k = blockIdx.x * 256 + threadIdx.x;
  if (mask[k]) {
    int idx = atomicAdd(count, 1);
    outlist[idx] = k;
  }
}

// ---------------------------------------------------------------------------
// Kernel 3: weight quant: zero outlier cols, per-row absmax -> q_scale, int8
// ---------------------------------------------------------------------------
__global__ __launch_bounds__(256) void k_wquant(
    const float* __restrict__ w, const int* __restrict__ mask,
    float* __restrict__ q_scale, int8_t* __restrict__ qw)
{
  const int n = blockIdx.x;
  const int t = threadIdx.x;
  const float4* wr = (const float4*)(w + (size_t)n * K_DIM);
  const int4* mr = (const int4*)mask;
  float4 v[4];
  float amax = 0.0f;
#pragma unroll
  for (int i = 0; i < 4; ++i) {
    float4 vv = wr[t + i * 256];
    int4 mm = mr[t + i * 256];
    vv.x = mm.x ? 0.0f : vv.x;
    vv.y = mm.y ? 0.0f : vv.y;
    vv.z = mm.z ? 0.0f : vv.z;
    vv.w = mm.w ? 0.0f : vv.w;
    v[i] = vv;
    amax = fmaxf(amax, fmaxf(fmaxf(fabsf(vv.x), fabsf(vv.y)),
                             fmaxf(fabsf(vv.z), fabsf(vv.w))));
  }
#pragma unroll
  for (int off = 32; off > 0; off >>= 1)
    amax = fmaxf(amax, __shfl_down(amax, off, 64));
  __shared__ float smax[4];
  __shared__ float sscale;
  if ((t & 63) == 0) smax[t >> 6] = amax;
  __syncthreads();
  if (t == 0) {
    float ms = fmaxf(fmaxf(smax[0], smax[1]), fmaxf(smax[2], smax[3]));
    float qs = fmaxf(ms / 127.0f, EPSQ);
    sscale = qs;
    q_scale[n] = qs;
  }
  __syncthreads();
  const float qs = sscale;
  uint32_t* qwo = (uint32_t*)(qw + (size_t)n * K_DIM);
#pragma unroll
  for (int i = 0; i < 4; ++i) {
    int q0 = (int)rintf(fminf(fmaxf(v[i].x / qs, -128.0f), 127.0f));
    int q1 = (int)rintf(fminf(fmaxf(v[i].y / qs, -128.0f), 127.0f));
    int q2 = (int)rintf(fminf(fmaxf(v[i].z / qs, -128.0f), 127.0f));
    int q3 = (int)rintf(fminf(fmaxf(v[i].w / qs, -128.0f), 127.0f));
    uint32_t packed = (uint32_t)(q0 & 0xff) | ((uint32_t)(q1 & 0xff) << 8) |
                      ((uint32_t)(q2 & 0xff) << 16) | ((uint32_t)(q3 & 0xff) << 24);
    qwo[t + i * 256] = packed;
  }
}

// ---------------------------------------------------------------------------
// Kernel 4: int8 GEMM, BK=64 (R1's better-measured structure), 64B LDS rows
// with 2-row-unit XOR chunk swizzle: c_phys = c_log ^ ((row>>1)&3).
// Quarter-wave ds_read_b128 then covers all 32 banks at 2-way (free).
// Swizzle applied on the GLOBAL source side for staging (GLDS dest must stay
// base + lane*16) and on the precomputed LDS read offsets.
// 128x128 tile, 256 threads = 4 waves (2x2), each wave 4x4 of 16x16x64.
// ---------------------------------------------------------------------------
__global__ __launch_bounds__(256) void k_gemm(
    const int8_t* __restrict__ qx, const int8_t* __restrict__ qw,
    const float* __restrict__ row_scale, const float* __restrict__ q_scale,
    const float* __restrict__ bias,
    const float* __restrict__ x, const float* __restrict__ w,
    const int* __restrict__ outlist, const int* __restrict__ outcount,
    float* __restrict__ out)
{
  __shared__ int8_t As[128 * 64];   // 8 KB, row stride 64B
  __shared__ int8_t Bs[128 * 64];   // 8 KB
  __shared__ float xsh[128][8];
  __shared__ float wsh[128][8];

  const int t = threadIdx.x;
  const int m0 = blockIdx.y * 128;
  const int n0 = blockIdx.x * 128;

  const int lane = t & 63;
  const int wave = t >> 6;
  const int wm = (wave & 1) * 64;
  const int wn = (wave >> 1) * 64;
  const int lrow = lane & 15;
  const int kg = lane >> 4;  // 0..3

  i32x4 acc[4][4] = {};

  // staging: slot t -> row = t>>2 (+64 for 2nd half), c_phys = t&3
  // logical chunk fetched for that slot: c_log = c_phys ^ ((row>>1)&3)
  const int srow = t >> 2;
  const int clog = (t & 3) ^ ((t >> 3) & 3);
  const int8_t* gA = qx + (size_t)(m0 + srow) * K_DIM + clog * 16;
  const int8_t* gB = qw + (size_t)(n0 + srow) * K_DIM + clog * 16;

  // loop-invariant swizzled LDS read offsets
  int offA[4], offB[4];
#pragma unroll
  for (int i = 0; i < 4; ++i) {
    int rA = wm + i * 16 + lrow;
    offA[i] = rA * 64 + ((kg ^ ((rA >> 1) & 3)) * 16);
    int rB = wn + i * 16 + lrow;
    offB[i] = rB * 64 + ((kg ^ ((rB >> 1) & 3)) * 16);
  }

  for (int k0 = 0; k0 < K_DIM; k0 += 64) {
    GLDS16(gA + k0,                        As + t * 16);
    GLDS16(gA + (size_t)64 * K_DIM + k0,   As + 4096 + t * 16);
    GLDS16(gB + k0,                        Bs + t * 16);
    GLDS16(gB + (size_t)64 * K_DIM + k0,   Bs + 4096 + t * 16);
    __syncthreads();

    i32x4 af[4], bf[4];
#pragma unroll
    for (int i = 0; i < 4; ++i) af[i] = *(const i32x4*)(As + offA[i]);
#pragma unroll
    for (int j = 0; j < 4; ++j) bf[j] = *(const i32x4*)(Bs + offB[j]);
#pragma unroll
    for (int i = 0; i < 4; ++i)
#pragma unroll
      for (int j = 0; j < 4; ++j)
        acc[i][j] = __builtin_amdgcn_mfma_i32_16x16x64_i8(af[i], bf[j], acc[i][j], 0, 0, 0);
    __syncthreads();
  }

  // ---- epilogue: stage outlier x / w slices into LDS ----
  const int cnt = *outcount;
  const int cs = cnt < 8 ? cnt : 8;
#pragma unroll
  for (int u = 0; u < 4; ++u) {
    int idx = t * 4 + u;   // 0..1023
    int rr = idx >> 3;     // 0..127
    int oo = idx & 7;
    float xv = 0.0f, wv = 0.0f;
    if (oo < cs) {
      int kcol = outlist[oo];
      xv = x[(size_t)(m0 + rr) * K_DIM + kcol];
      wv = w[(size_t)(n0 + rr) * K_DIM + kcol];
    }
    xsh[rr][oo] = xv;
    wsh[rr][oo] = wv;
  }
  __syncthreads();

  float qs[4], bv[4];
  int gn[4];
#pragma unroll
  for (int j = 0; j < 4; ++j) {
    gn[j] = n0 + wn + j * 16 + lrow;
    qs[j] = q_scale[gn[j]];
    bv[j] = bias[gn[j]];
  }

  // C/D layout: col = lane&15, row = (lane>>4)*4 + reg  [m89/m101, dtype-indep]
#pragma unroll
  for (int i = 0; i < 4; ++i) {
#pragma unroll
    for (int r = 0; r < 4; ++r) {
      int ml = wm + i * 16 + kg * 4 + r;
      int gm = m0 + ml;
      float rs = row_scale[gm];
      float xvv[8];
#pragma unroll
      for (int o = 0; o < 8; ++o) xvv[o] = xsh[ml][o];
#pragma unroll
      for (int j = 0; j < 4; ++j) {
        int nl = wn + j * 16 + lrow;
        float corr = 0.0f;
#pragma unroll
        for (int o = 0; o < 8; ++o) corr += xvv[o] * wsh[nl][o];
        for (int o = 8; o < cnt; ++o)   // generality fallback (cold in practice)
          corr += x[(size_t)gm * K_DIM + outlist[o]] *
                  w[(size_t)gn[j] * K_DIM + outlist[o]];
        float val = (float)acc[i][j][r] * rs * qs[j] + corr + bv[j];
        out[(size_t)gm * N_DIM + gn[j]] = val;
      }
    }
  }
}

// ---------------------------------------------------------------------------
extern "C" void kernel_launch(void* const* d_in, const int* in_sizes, int n_in,
                              void* d_out, int out_size, void* d_ws, size_t ws_size,
                              hipStream_t stream) {
  const float* x = (const float*)d_in[0];      // [M,K] fp32 (M = B*S)
  const float* w = (const float*)d_in[1];      // [N,K] fp32
  const float* bias = (const float*)d_in[2];   // [N]
  float* out = (float*)d_out;                  // [M,N] fp32
  const int M = in_sizes[0] / K_DIM;           // 4096

  // workspace layout
  char* ws = (char*)d_ws;
  int* mask = (int*)(ws);                          // 16 KB
  int* count = (int*)(ws + 16384);                 // 4 B (memset region)
  int* outlist = (int*)(ws + 20480);               // 16 KB
  float* row_scale = (float*)(ws + 36864);         // 16 KB
  float* q_scale = (float*)(ws + 53248);           // 16 KB
  int8_t* qx = (int8_t*)(ws + 131072);             // M*K int8 = 16 MB
  int8_t* qw = (int8_t*)(ws + 131072 + (size_t)M * K_DIM);  // N*K int8 = 16 MB

  hipMemsetAsync(ws, 0, 20480, stream);  // mask + count
  k_rowquant<<<M, 256, 0, stream>>>(x, row_scale, mask, qx);
  k_compact<<<K_DIM / 256, 256, 0, stream>>>(mask, outlist, count);
  k_wquant<<<N_DIM, 256, 0, stream>>>(w, mask, q_scale, qw);
  dim3 grid(N_DIM / 128, M / 128);
  k_gemm<<<grid, dim3(256, 1, 1), 0, stream>>>(qx, qw, row_scale, q_scale, bias,
                                               x, w, outlist, count, out);
}